// Round 13
// baseline (18.556 us; speedup 1.0000x reference)
//
#include <hip/hip_runtime.h>

#define N_ 2048
#define F_ 128

// workspace (u64 units) — P1/SF padded to 1 record per 64B line (stride 8)
#define WS_P1 0       // [8*64]  records at P1[i*8]
#define WS_SF 4096    // [8*256] records at SF[i*8]
#define WS_P2 20480   // [8][64][256] packed: P2[(b*64+kb)*256 + cv]

typedef __attribute__((ext_vector_type(8))) short short8v;
typedef __attribute__((ext_vector_type(4))) float f32x4;
typedef unsigned long long u64;

__device__ inline short f2bf(float f) {
    union { float f; unsigned u; } c; c.f = f;
    unsigned r = (c.u + 0x7FFFu + ((c.u >> 16) & 1u)) >> 16;
    return (short)r;
}
__device__ inline void store_pair(u64* p, float f) {
    union { float f; unsigned u; } c; c.f = f;
    const u64 v = ((u64)(~c.u) << 32) | (u64)c.u;
    __hip_atomic_store(p, v, __ATOMIC_RELAXED, __HIP_MEMORY_SCOPE_AGENT);
}
__device__ inline bool pair_ok(u64 v) {
    return (unsigned)(v >> 32) == (unsigned)(~(unsigned)v);
}
__device__ inline float pair_val(u64 v) {
    union { unsigned u; float f; } c; c.u = (unsigned)v;
    return c.f;
}
// spin with backoff: first check free; on miss sleep ~1024 cyc between polls
__device__ inline u64 spin_load(u64* p) {
    u64 v = __hip_atomic_load(p, __ATOMIC_RELAXED, __HIP_MEMORY_SCOPE_AGENT);
    while (!pair_ok(v)) {
        __builtin_amdgcn_s_sleep(16);
        v = __hip_atomic_load(p, __ATOMIC_RELAXED, __HIP_MEMORY_SCOPE_AGENT);
    }
    return v;
}

// DEADLOCK RULE (r8): spin producer sets contiguous in blockIdx (b = bid>>6).
// LAYOUT RULE (r9): bulk publishes/gathers wave-coalesced (P2 packed).
// CONTENTION RULE (r13): multi-poller records get 1 line each + backoff.
__global__ __launch_bounds__(256, 2) void gcn_one(
    const float* __restrict__ x, const float* __restrict__ adj_w,
    const float* __restrict__ adj_b_p, const float* __restrict__ weight,
    const float* __restrict__ bias, float* __restrict__ outx,
    u64* __restrict__ P1, u64* __restrict__ SF, u64* __restrict__ P2)
{
    __shared__ unsigned short wt[128 * 128];   // W^T bf16, slot-swizzled (32 KB)
    __shared__ float adjw[256];
    __shared__ float ail[32], ajl[32], disl[32], ajdl[32];
    __shared__ float red0[2][128], red1[2][128];
    __shared__ float s0l[128], s1l[128], bl[128];
    __shared__ float Ash;

    const int bid = blockIdx.x;                 // 0..511
    const int b = bid >> 6;                     // contiguous producer chunks
    const int kbme = bid & 63;                  // 0..63
    const int r0 = kbme * 32;
    const int t = threadIdx.x;                  // 0..255
    const int lane = t & 63, w = t >> 6;        // 4 waves
    const int u = lane & 15, g = lane >> 4;
    const int wr = (w & 1) * 16;                // row-group (0 or 16)
    const int ct0 = (w >> 1) * 4;               // col-tile base (0 or 4)

    const float adjb = adj_b_p[0];
    adjw[t] = adj_w[t];
    if (t < 128) bl[t] = bias[t];
    __syncthreads();

    // ---- phase 1: read x ONCE in MFMA A-layout; a_i/a_j via in-lane + shfl
    const float* xrow = x + (size_t)(b * N_ + r0 + wr + u) * F_;
    float4 xa[4], xb[4];
    #pragma unroll
    for (int kk = 0; kk < 4; ++kk) {
        xa[kk] = *reinterpret_cast<const float4*>(xrow + kk * 32 + g * 8);
        xb[kk] = *reinterpret_cast<const float4*>(xrow + kk * 32 + g * 8 + 4);
    }
    {
        float ai = 0.f, aj = 0.f;
        #pragma unroll
        for (int kk = 0; kk < 4; ++kk) {
            const float va[4] = {xa[kk].x, xa[kk].y, xa[kk].z, xa[kk].w};
            const float vb[4] = {xb[kk].x, xb[kk].y, xb[kk].z, xb[kk].w};
            #pragma unroll
            for (int i = 0; i < 4; ++i) {
                const int k = kk * 32 + g * 8 + i;
                ai = fmaf(va[i], adjw[k], ai);
                aj = fmaf(va[i], adjw[128 + k], aj);
                ai = fmaf(vb[i], adjw[k + 4], ai);
                aj = fmaf(vb[i], adjw[128 + k + 4], aj);
            }
        }
        ai += __shfl_xor(ai, 16, 64); ai += __shfl_xor(ai, 32, 64);
        aj += __shfl_xor(aj, 16, 64); aj += __shfl_xor(aj, 32, 64);
        if (w < 2 && g == 0) {
            ail[wr + u] = ai + adjb;
            ajl[wr + u] = aj;
        }
    }
    __syncthreads();
    // publish tagged a_j partial ASAP (padded line)
    if (t < 32) {
        float s = ajl[t];
        #pragma unroll
        for (int off = 16; off > 0; off >>= 1) s += __shfl_down(s, off, 64);
        if (t == 0) store_pair(&P1[(b * 64 + kbme) * 8], s);
    }

    // ---- stage W^T bf16 (barrier-independent; hides P1 propagation)
    {
        const int c = t & 127, khalf = t >> 7;
        for (int j8 = 0; j8 < 8; ++j8) {
            const int kb = khalf * 8 + j8;
            short8v v;
            #pragma unroll
            for (int i = 0; i < 8; ++i)
                v[i] = f2bf(weight[(kb * 8 + i) * F_ + c]);
            const int slot = kb ^ (c & 15);
            *reinterpret_cast<short8v*>(&wt[c * 128 + slot * 8]) = v;
        }
    }
    __syncthreads();

    // ---- MFMA GEMM from registers (still barrier-independent)
    f32x4 acc[4];
    #pragma unroll
    for (int i = 0; i < 4; ++i) acc[i] = (f32x4)(0.f);
    #pragma unroll
    for (int kk = 0; kk < 4; ++kk) {
        short8v af;
        af[0] = f2bf(xa[kk].x); af[1] = f2bf(xa[kk].y);
        af[2] = f2bf(xa[kk].z); af[3] = f2bf(xa[kk].w);
        af[4] = f2bf(xb[kk].x); af[5] = f2bf(xb[kk].y);
        af[6] = f2bf(xb[kk].z); af[7] = f2bf(xb[kk].w);
        const int kb = kk * 4 + g;
        #pragma unroll
        for (int c = 0; c < 4; ++c) {
            const int col = (ct0 + c) * 16 + u;
            const int slot = kb ^ u;            // col&15 == u
            const short8v bfv = *reinterpret_cast<const short8v*>(&wt[col * 128 + slot * 8]);
            acc[c] = __builtin_amdgcn_mfma_f32_16x16x32_bf16(af, bfv, acc[c], 0, 0, 0);
        }
    }

    // ---- barrier A: lane t polls record t (1 line each, backoff)
    if (t < 64) {
        float s = pair_val(spin_load(&P1[(b * 64 + t) * 8]));
        #pragma unroll
        for (int off = 32; off > 0; off >>= 1) s += __shfl_down(s, off, 64);
        if (t == 0) Ash = s;
    }
    __syncthreads();
    if (t < 32) {
        const float deg = fmaxf(2048.f * ail[t] + Ash + 1.f, 1.f);
        const float d = rsqrtf(deg);
        disl[t] = d;
        ajdl[t] = ajl[t] * d;
    }
    __syncthreads();

    // ---- s-partials DIRECTLY from MFMA accumulators
    #pragma unroll
    for (int c = 0; c < 4; ++c) {
        float s0 = 0.f, s1 = 0.f;
        #pragma unroll
        for (int r = 0; r < 4; ++r) {
            const int row = wr + g * 4 + r;
            s0 = fmaf(disl[row], acc[c][r], s0);
            s1 = fmaf(ajdl[row], acc[c][r], s1);
        }
        s0 += __shfl_xor(s0, 16, 64); s0 += __shfl_xor(s0, 32, 64);
        s1 += __shfl_xor(s1, 16, 64); s1 += __shfl_xor(s1, 32, 64);
        if (g == 0) {
            red0[w & 1][(ct0 + c) * 16 + u] = s0;
            red1[w & 1][(ct0 + c) * 16 + u] = s1;
        }
    }
    __syncthreads();
    // ---- stage 1 publish: all 256 threads, coalesced (cv = t, c = t>>1)
    {
        const int c = t >> 1;
        const float v = (t & 1) ? (red1[0][c] + red1[1][c])
                                : (red0[0][c] + red0[1][c]);
        store_pair(&P2[(size_t)(b * 64 + kbme) * 256 + t], v);
    }

    // ---- stage 2: finalize cv = kbme*4 + w (1 poller per record, backoff)
    {
        const int cv = kbme * 4 + w;
        float s = pair_val(spin_load(&P2[(size_t)(b * 64 + lane) * 256 + cv]));
        #pragma unroll
        for (int off = 32; off > 0; off >>= 1) s += __shfl_down(s, off, 64);
        if (lane == 0) store_pair(&SF[(b * 256 + cv) * 8], s);
    }

    // ---- stage 3: thread t polls final t (padded line, backoff)
    {
        const float sv = pair_val(spin_load(&SF[(b * 256 + t) * 8]));
        if ((t & 1) == 0) s0l[t >> 1] = sv; else s1l[t >> 1] = sv;
    }
    __syncthreads();

    // ---- epilogue on MFMA accumulators, single out write
    #pragma unroll
    for (int c = 0; c < 4; ++c) {
        const int col = (ct0 + c) * 16 + u;
        const float sv0 = s0l[col], sv1 = s1l[col], bv = bl[col];
        #pragma unroll
        for (int r = 0; r < 4; ++r) {
            const int row = wr + g * 4 + r;
            const float d = disl[row], ab = ail[row];
            const float o = fmaxf(d * (ab * sv0 + sv1 + d * acc[c][r]) + bv, 0.f);
            outx[(size_t)(b * N_ + r0 + row) * F_ + col] = o;
        }
    }
}

extern "C" void kernel_launch(void* const* d_in, const int* in_sizes, int n_in,
                              void* d_out, int out_size, void* d_ws, size_t ws_size,
                              hipStream_t stream) {
    const float* x      = (const float*)d_in[0];
    const float* adj_w  = (const float*)d_in[1];
    const float* adj_b  = (const float*)d_in[2];
    const float* weight = (const float*)d_in[3];
    const float* bias   = (const float*)d_in[4];
    float* out = (float*)d_out;
    u64* ws = (u64*)d_ws;

    gcn_one<<<512, 256, 0, stream>>>(x, adj_w, adj_b, weight, bias, out,
                                     ws + WS_P1, ws + WS_SF, ws + WS_P2);
}